// Round 14
// baseline (654.557 us; speedup 1.0000x reference)
//
#include <hip/hip_runtime.h>

#define TTs 50
#define NSTEP 49

using short8   = __attribute__((ext_vector_type(8))) short;
using ushort4v = __attribute__((ext_vector_type(4))) unsigned short;
using f32x4    = __attribute__((ext_vector_type(4))) float;
using int4v    = __attribute__((ext_vector_type(4))) int;

__device__ __forceinline__ unsigned short f2bf(float f) {
    unsigned u = __builtin_bit_cast(unsigned, f);
    u += 0x7FFFu + ((u >> 16) & 1u);          // RNE
    return (unsigned short)(u >> 16);
}
__device__ __forceinline__ float bf2f(unsigned short s) {
    unsigned u = ((unsigned)s) << 16;
    return __builtin_bit_cast(float, u);
}
__device__ __forceinline__ float frcp(float x) { return __builtin_amdgcn_rcpf(x); }
// rcp-based: exp overflow -> inf -> rcp -> 0 (correct saturation)
__device__ __forceinline__ float sigm(float x)  { return frcp(1.f + __expf(-x)); }
__device__ __forceinline__ float ftanh(float x) { return 1.f - 2.f * frcp(__expf(2.f * x) + 1.f); }

#define WH_SCALE 512.f
#define H_SCALE  127.f

// Counting sort of the 1024 rows by length, DESCENDING. perm[rank] = orig row.
__global__ __launch_bounds__(1024)
void sort_kernel(const int* __restrict__ lenq, const int* __restrict__ lenr,
                 int* __restrict__ perm, float* __restrict__ out)
{
    __shared__ int cnt[64];
    const int tid = threadIdx.x;
    if (tid == 0) out[0] = 0.f;
    if (tid < 64) cnt[tid] = 0;
    __syncthreads();
    const int l = (tid < 512) ? lenq[tid] : lenr[tid - 512];   // 1..49
    atomicAdd(&cnt[l], 1);
    __syncthreads();
    if (tid == 0) {
        int acc = 0;
        for (int v = 49; v >= 1; --v) { int c = cnt[v]; cnt[v] = acc; acc += c; }
    }
    __syncthreads();
    const int rank = atomicAdd(&cnt[l], 1);
    perm[rank] = tid;
}

// Pack W (f32 [512][1024]):
//  y=0: Wx rows 0..255   -> Wxp bf16 [c][k] col-major frag layout
//  y=1: Wh rows 256..511 -> Wq  int8 [c][k] col-major, scaled by 512
__global__ __launch_bounds__(256)
void pack_w_kernel(const float* __restrict__ W,
                   unsigned short* __restrict__ Wxp, signed char* __restrict__ Wq)
{
    __shared__ float ld[64][65];
    const int koff = blockIdx.y * 256;
    const int k0 = (blockIdx.x & 3) * 64, c0 = (blockIdx.x >> 2) * 64;
    const int tid = threadIdx.x;
    #pragma unroll
    for (int i = 0; i < 16; ++i) {
        int idx = tid + i * 256;
        ld[idx >> 6][idx & 63] = W[(size_t)(koff + k0 + (idx >> 6)) * 1024 + c0 + (idx & 63)];
    }
    __syncthreads();
    if (blockIdx.y == 0) {
        #pragma unroll
        for (int j = 0; j < 2; ++j) {
            int idx = tid + j * 256;
            int cl = idx >> 3, kc = (idx & 7) * 8;
            short8 v;
            #pragma unroll
            for (int e = 0; e < 8; ++e) v[e] = (short)f2bf(ld[kc + e][cl]);
            *(short8*)(Wxp + (size_t)(c0 + cl) * 256 + k0 + kc) = v;
        }
    } else {
        #pragma unroll
        for (int j = 0; j < 2; ++j) {
            int idx = tid + j * 256;
            int cl = idx >> 3, kc = (idx & 7) * 8;
            unsigned long long u = 0;
            #pragma unroll
            for (int e = 0; e < 8; ++e) {
                float v = ld[kc + e][cl] * WH_SCALE;
                int q = __float2int_rn(fminf(fmaxf(v, -127.f), 127.f));
                u |= (unsigned long long)(unsigned char)(signed char)q << (8 * e);
            }
            *(unsigned long long*)(Wq + (size_t)(c0 + cl) * 256 + k0 + kc) = u;
        }
    }
}

// X projection v5: rows processed in SORTED order (perm). Per-it whole-tile
// skip when t >= max length in the tile (sorted desc -> first row is max).
// Wx register-resident; block = 512 thr owns a 256-col slice (y of 4),
// sweeps 4 row-tiles. Bias (+FORGET_BIAS) folded into the stored X.
// X element offset: t*1048576 + rblk*16384 + slot*256 + L*4  (slot = zcol/16)
__global__ __launch_bounds__(512, 4)
void xproj_kernel(const float* __restrict__ emb,
                  const int* __restrict__ idq, const int* __restrict__ idr,
                  const int* __restrict__ lenq, const int* __restrict__ lenr,
                  const int* __restrict__ perm,
                  const unsigned short* __restrict__ Wxp,
                  const float* __restrict__ bias,
                  unsigned short* __restrict__ X)
{
    __shared__ __align__(16) unsigned short As[64 * 264];   // 33 KB
    __shared__ int Ls2[4][64];
    __shared__ int Ids2[4][64];
    __shared__ int Tmax[4];

    const int tid = threadIdx.x;
    const int L = tid & 63, w = tid >> 6;          // 8 waves
    const int lanelo = L & 15, lhi = L >> 4;
    const int cslice = blockIdx.y;                 // 0..3
    const int colbase = cslice * 256 + w * 32;     // wave's 32 cols
    const int slot0 = cslice * 16 + w * 2;

    // ---- Wx slice -> registers (persistent) ----
    short8 Bx[2][8];
    #pragma unroll
    for (int cf = 0; cf < 2; ++cf) {
        const unsigned short* bb = Wxp + (size_t)(colbase + cf * 16 + lanelo) * 256 + lhi * 8;
        #pragma unroll
        for (int ks = 0; ks < 8; ++ks) Bx[cf][ks] = *(const short8*)(bb + ks * 32);
    }
    // per-lane bias for the two owned cols (incl. forget bias on gate 2)
    float bc[2];
    #pragma unroll
    for (int cf = 0; cf < 2; ++cf) {
        int col = colbase + cf * 16 + lanelo;
        bc[cf] = bias[col] + ((col >= 512 && col < 768) ? 2.0f : 0.f);
    }

    // ---- stage lens/ids (sorted order) for this block's 4 row-tiles ----
    if (tid < 256) {
        int it = tid >> 6, rl = tid & 63;
        int rt = blockIdx.x + it * 196;
        int t = rt >> 4, r0 = (rt & 15) * 64;
        int gr = perm[r0 + rl];
        int len = (gr < 512) ? lenq[gr] : lenr[gr - 512];
        Ls2[it][rl] = len;
        Ids2[it][rl] = (gr < 512) ? idq[gr * TTs + t] : idr[(gr - 512) * TTs + t];
        if (rl == 0) Tmax[it] = len;               // sorted desc -> max of tile
    }
    __syncthreads();

    for (int it = 0; it < 4; ++it) {
        const int rt = blockIdx.x + it * 196;
        const int t = rt >> 4;
        const int rblkb = (rt & 15) * 4;
        if (t >= Tmax[it]) continue;               // whole tile dead (uniform)
        const int* Ls = Ls2[it];
        const int* Ids = Ids2[it];

        // ---- stage gathered emb rows -> LDS (bf16), skip dead rows ----
        float4 ev0[4], ev1[4];
        bool live[4];
        #pragma unroll
        for (int i = 0; i < 4; ++i) {
            int task = tid + i * 512;
            int rl = task >> 5, kc = (task & 31) * 8;
            live[i] = (t < Ls[rl]);
            if (live[i]) {
                const float* ep = emb + (size_t)Ids[rl] * 256 + kc;
                ev0[i] = *(const float4*)ep;
                ev1[i] = *(const float4*)(ep + 4);
            }
        }
        #pragma unroll
        for (int i = 0; i < 4; ++i) {
            if (live[i]) {
                int task = tid + i * 512;
                int rl = task >> 5, kc = (task & 31) * 8;
                short8 v;
                v[0] = (short)f2bf(ev0[i].x); v[1] = (short)f2bf(ev0[i].y);
                v[2] = (short)f2bf(ev0[i].z); v[3] = (short)f2bf(ev0[i].w);
                v[4] = (short)f2bf(ev1[i].x); v[5] = (short)f2bf(ev1[i].y);
                v[6] = (short)f2bf(ev1[i].z); v[7] = (short)f2bf(ev1[i].w);
                *(short8*)(As + rl * 264 + kc) = v;
            }
        }
        __syncthreads();

        // ---- compute: 4 row-groups x (8 ds_read + 16 MFMA) ----
        #pragma unroll
        for (int rg = 0; rg < 4; ++rg) {
            int base = rg * 16 + lhi * 4;
            int lmax = max(max(Ls[base], Ls[base + 1]), max(Ls[base + 2], Ls[base + 3]));
            bool myalive = (t < lmax);
            if (__any(myalive)) {
                f32x4 a0 = (f32x4){0.f, 0.f, 0.f, 0.f};
                f32x4 a1 = (f32x4){0.f, 0.f, 0.f, 0.f};
                const unsigned short* ar = As + (rg * 16 + lanelo) * 264 + lhi * 8;
                #pragma unroll
                for (int ks = 0; ks < 8; ++ks) {
                    short8 a = *(const short8*)(ar + ks * 32);
                    a0 = __builtin_amdgcn_mfma_f32_16x16x32_bf16(a, Bx[0][ks], a0, 0, 0, 0);
                    a1 = __builtin_amdgcn_mfma_f32_16x16x32_bf16(a, Bx[1][ks], a1, 0, 0, 0);
                }
                if (myalive) {
                    size_t off = (((size_t)(t * 64 + rblkb + rg)) * 64 + slot0) * 256 + L * 4;
                    ushort4v v0, v1;
                    #pragma unroll
                    for (int j = 0; j < 4; ++j) {
                        v0[j] = f2bf(a0[j] + bc[0]);
                        v1[j] = f2bf(a1[j] + bc[1]);
                    }
                    *(ushort4v*)(X + off) = v0;
                    *(ushort4v*)(X + off + 256) = v1;
                }
            }
        }
        __syncthreads();   // protect As/Ls before next tile's staging
    }
}

// Recurrent loop v6: 512 blocks x 2 SORTED rows, 16 waves -> 2 blocks/CU.
// TLP fix: with one block/CU the barrier + gate-chain stall left SIMDs idle
// (~2/3 of the 2880-cyc step); a co-resident second block fills those slots.
// Live tile rows {0,8}: owner lanes lhi in {0,2} hold their cell in acc[g][0].
// h LDS = 2 rows x 288 B (<=2-way b128 conflict = free). Whq slice in AGPRs.
__global__ __launch_bounds__(1024, 8)
void lstm_i8_kernel(const unsigned short* __restrict__ X,
                    const signed char* __restrict__ Wq,
                    const float* __restrict__ p_i, const float* __restrict__ p_f,
                    const float* __restrict__ p_o,
                    const int* __restrict__ lenq, const int* __restrict__ lenr,
                    const int* __restrict__ perm,
                    unsigned short* __restrict__ hfin)
{
    __shared__ __align__(16) char hl[2 * 2 * 288];   // 1152 B, dbuf x 2 rows
    const int tid = threadIdx.x;
    const int L = tid & 63, w = tid >> 6;      // w 0..15
    const int blk = blockIdx.x;                // 2 sorted rows each
    const int lanelo = L & 15, lhi = L >> 4;
    const int hh = w * 16 + lanelo;
    const int r = lhi >> 1;                    // row this lane's gate serves
    const bool owner = (lhi & 1) == 0;         // lhi in {0,2} own live cells

    if (tid < 288) ((int*)hl)[tid] = 0;

    // ---- Wh slice (int8) -> registers (AGPR-resident), persistent ----
    int4v Bw[4][4];
    #pragma unroll
    for (int g = 0; g < 4; ++g)
        #pragma unroll
        for (int kc = 0; kc < 4; ++kc)
            Bw[g][kc] = *(const int4v*)(Wq + (size_t)(g * 256 + hh) * 256 + kc * 64 + lhi * 16);

    // X addressing (sorted positions): tile rblk16 = blk>>3,
    // tile row tr = (blk&7)*2 + r.
    // ushort element: (g*16+w)*256 + (tr>>2)*64 + lanelo*4 + (tr&3)
    const unsigned short* xb = X + (size_t)(blk >> 3) * 16384;
    const int tr = (blk & 7) * 2 + r;
    int xgoff[4];
    #pragma unroll
    for (int g = 0; g < 4; ++g)
        xgoff[g] = (g * 16 + w) * 256 + (tr >> 2) * 64 + lanelo * 4 + (tr & 3);

    const bool rdlane = (lanelo & 7) == 0;     // 8 lanes read; rest hold zeros
    const int ard = (lanelo >> 3) * 288 + lhi * 16;  // live row = lanelo>>3
    const int awr = r * 288 + hh;                    // owner writes row r

    const float pii = p_i[hh], pff = p_f[hh], poo = p_o[hh];
    const float INV = 1.f / (H_SCALE * WH_SCALE);

    const int gr = perm[blk * 2 + r];
    const int len_ = (gr < 512) ? lenq[gr] : lenr[gr - 512];
    const int p0 = perm[blk * 2];
    const int blkmax = (p0 < 512) ? lenq[p0] : lenr[p0 - 512];  // uniform

    float cst = 0.f;
    float hst = 0.f;

    // A-fragments: rows != 8k are permanently zero (init hoisted out of loop)
    int4v a[4];
    #pragma unroll
    for (int kc = 0; kc < 4; ++kc) a[kc] = (int4v){0, 0, 0, 0};

    // preload X for t = 0 (always written: len >= 1)
    unsigned short xr[4], xn[4];
    #pragma unroll
    for (int g = 0; g < 4; ++g) xr[g] = xb[xgoff[g]];
    const unsigned short* xp = xb + 1048576;   // scalar, advances 1 MB/step

    __syncthreads();

    for (int t = 0; t < blkmax; ++t) {
        const int rb = (t & 1) * 576;
        const int wb = 576 - rb;

        // prefetch next step (uniform cselect keeps the last read in-bounds)
        const unsigned short* xs = (t + 1 < blkmax) ? xp : xb;
        #pragma unroll
        for (int g = 0; g < 4; ++g) xn[g] = xs[xgoff[g]];
        xp += 1048576;

        if (rdlane) {
            #pragma unroll
            for (int kc = 0; kc < 4; ++kc)
                a[kc] = *(const int4v*)(hl + rb + ard + kc * 64);
        }

        int4v acc[4];
        #pragma unroll
        for (int g = 0; g < 4; ++g) acc[g] = (int4v){0, 0, 0, 0};
        #pragma unroll
        for (int kc = 0; kc < 4; ++kc)
            #pragma unroll
            for (int g = 0; g < 4; ++g)
                acc[g] = __builtin_amdgcn_mfma_i32_16x16x64_i8(a[kc], Bw[g][kc], acc[g], 0, 0, 0);

        {
            float cv = cst;
            float zi = fmaf((float)acc[0][0], INV, bf2f(xr[0]));
            float zj = fmaf((float)acc[1][0], INV, bf2f(xr[1]));
            float zf = fmaf((float)acc[2][0], INV, bf2f(xr[2]));
            float zo = fmaf((float)acc[3][0], INV, bf2f(xr[3]));
            float iv = sigm(fmaf(pii, cv, zi));
            float fv = sigm(fmaf(pff, cv, zf));
            float jv = ftanh(zj);
            float cn = fv * cv + iv * jv;
            float ov = sigm(fmaf(poo, cn, zo));
            float hn = ov * ftanh(cn);
            bool upd = (t < len_);
            if (upd) { cst = cn; hst = hn; }
            if (owner)
                hl[wb + awr] = (signed char)__float2int_rn(hst * H_SCALE);
        }
        __syncthreads();
        #pragma unroll
        for (int g = 0; g < 4; ++g) xr[g] = xn[g];
    }

    if (owner)
        hfin[(size_t)gr * 256 + hh] = f2bf(hst);
}

#define TS 64
#define KT 16
#define LDW (TS + 4)

// qM[512x256] = bf16 h(rows 0..511) @ fp32 M[256x256]
__global__ __launch_bounds__(256)
void gemm_qM_kernel(const unsigned short* __restrict__ hA, const float* __restrict__ B,
                    float* __restrict__ C)
{
    __shared__ float As[KT][LDW];
    __shared__ float Bs[KT][LDW];
    const int tid = threadIdx.x;
    const int tx = tid & 15, ty = tid >> 4;
    const int m0 = blockIdx.x * TS, n0 = blockIdx.y * TS;
    float acc[4][4] = {};
    for (int kk = 0; kk < 256; kk += KT) {
        #pragma unroll
        for (int i = 0; i < 4; ++i) {
            int l = tid + i * 256;
            As[l & 15][l >> 4] = bf2f(hA[(m0 + (l >> 4)) * 256 + kk + (l & 15)]);
            Bs[l >> 6][l & 63] = B[(kk + (l >> 6)) * 256 + n0 + (l & 63)];
        }
        __syncthreads();
        #pragma unroll
        for (int k = 0; k < KT; ++k) {
            float4 a4 = *(const float4*)&As[k][ty * 4];
            float4 b4 = *(const float4*)&Bs[k][tx * 4];
            float av[4] = {a4.x, a4.y, a4.z, a4.w};
            float bv[4] = {b4.x, b4.y, b4.z, b4.w};
            #pragma unroll
            for (int i = 0; i < 4; ++i)
                #pragma unroll
                for (int j = 0; j < 4; ++j)
                    acc[i][j] = fmaf(av[i], bv[j], acc[i][j]);
        }
        __syncthreads();
    }
    #pragma unroll
    for (int i = 0; i < 4; ++i) {
        float4 v = {acc[i][0], acc[i][1], acc[i][2], acc[i][3]};
        *(float4*)&C[(m0 + ty * 4 + i) * 256 + n0 + tx * 4] = v;
    }
}

// D[512x512] = fp32 qM[512x256] @ (bf16 r[512x256])^T
__global__ __launch_bounds__(256)
void gemm_D_kernel(const float* __restrict__ A, const unsigned short* __restrict__ hB,
                   float* __restrict__ C)
{
    __shared__ float As[KT][LDW];
    __shared__ float Bs[KT][LDW];
    const int tid = threadIdx.x;
    const int tx = tid & 15, ty = tid >> 4;
    const int m0 = blockIdx.x * TS, n0 = blockIdx.y * TS;
    float acc[4][4] = {};
    for (int kk = 0; kk < 256; kk += KT) {
        #pragma unroll
        for (int i = 0; i < 4; ++i) {
            int l = tid + i * 256;
            As[l & 15][l >> 4] = A[(m0 + (l >> 4)) * 256 + kk + (l & 15)];
            Bs[l & 15][l >> 4] = bf2f(hB[(n0 + (l >> 4)) * 256 + kk + (l & 15)]);
        }
        __syncthreads();
        #pragma unroll
        for (int k = 0; k < KT; ++k) {
            float4 a4 = *(const float4*)&As[k][ty * 4];
            float4 b4 = *(const float4*)&Bs[k][tx * 4];
            float av[4] = {a4.x, a4.y, a4.z, a4.w};
            float bv[4] = {b4.x, b4.y, b4.z, b4.w};
            #pragma unroll
            for (int i = 0; i < 4; ++i)
                #pragma unroll
                for (int j = 0; j < 4; ++j)
                    acc[i][j] = fmaf(av[i], bv[j], acc[i][j]);
        }
        __syncthreads();
    }
    #pragma unroll
    for (int i = 0; i < 4; ++i) {
        float4 v = {acc[i][0], acc[i][1], acc[i][2], acc[i][3]};
        *(float4*)&C[(m0 + ty * 4 + i) * 512 + n0 + tx * 4] = v;
    }
}

__global__ __launch_bounds__(256)
void loss_kernel(const float* __restrict__ D, const float* __restrict__ wd,
                 float* __restrict__ out)
{
    int idx = blockIdx.x * 256 + threadIdx.x;
    int j = idx & 511;
    float d   = D[idx];
    float pos = D[j * 512 + j];
    float ww  = wd[idx];
    float wp  = wd[j * 512 + j];
    float wn  = fmaxf(0.f, fmaf(ww, frcp(wp), -1.f));
    float v   = fmaxf(0.f, d - pos + wn);
    #pragma unroll
    for (int o = 32; o > 0; o >>= 1) v += __shfl_down(v, o);
    __shared__ float sm[4];
    if ((threadIdx.x & 63) == 0) sm[threadIdx.x >> 6] = v;
    __syncthreads();
    if (threadIdx.x == 0) atomicAdd(out, sm[0] + sm[1] + sm[2] + sm[3]);
}

extern "C" void kernel_launch(void* const* d_in, const int* in_sizes, int n_in,
                              void* d_out, int out_size, void* d_ws, size_t ws_size,
                              hipStream_t stream) {
    const int*   idq  = (const int*)d_in[0];
    const int*   idr  = (const int*)d_in[1];
    const int*   lenq = (const int*)d_in[2];
    const int*   lenr = (const int*)d_in[3];
    const float* wd   = (const float*)d_in[4];
    const float* emb  = (const float*)d_in[5];
    const float* W    = (const float*)d_in[6];
    const float* bias = (const float*)d_in[7];
    const float* p_i  = (const float*)d_in[8];
    const float* p_f  = (const float*)d_in[9];
    const float* p_o  = (const float*)d_in[10];
    const float* Mm   = (const float*)d_in[11];
    float* out = (float*)d_out;

    char* ws = (char*)d_ws;
    unsigned short* X    = (unsigned short*)ws;           // 49*1024*1024 bf16 = 102,760,448 B
    char* p = ws + (size_t)NSTEP * 1048576 * 2;
    unsigned short* hfin = (unsigned short*)p;  p += 1024 * 256 * 2;   // 512 KB
    unsigned short* Wxp  = (unsigned short*)p;  p += 1024 * 256 * 2;   // 512 KB
    signed char*    Wq   = (signed char*)p;     p += 1024 * 256;       // 256 KB
    float* qM = (float*)p;  p += 512 * 256 * 4;                        // 512 KB
    float* D  = (float*)p;  p += 512 * 512 * 4;                        // 1 MB
    int* perm = (int*)p;                                               // 4 KB

    sort_kernel<<<1, 1024, 0, stream>>>(lenq, lenr, perm, out);
    pack_w_kernel<<<dim3(64, 2), 256, 0, stream>>>(W, Wxp, Wq);
    xproj_kernel<<<dim3(196, 4), 512, 0, stream>>>(emb, idq, idr, lenq, lenr,
                                                   perm, Wxp, bias, X);
    lstm_i8_kernel<<<512, 1024, 0, stream>>>(X, Wq, p_i, p_f, p_o,
                                             lenq, lenr, perm, hfin);
    gemm_qM_kernel<<<dim3(8, 4), 256, 0, stream>>>(hfin, Mm, qM);
    gemm_D_kernel<<<dim3(8, 8), 256, 0, stream>>>(qM, hfin + 512 * 256, D);
    loss_kernel<<<1024, 256, 0, stream>>>(D, wd, out);
}

// Round 15
// 150.143 us; speedup vs baseline: 4.3596x; 4.3596x over previous
//
#include <hip/hip_runtime.h>

#define TTs 50
#define NSTEP 49

using short8   = __attribute__((ext_vector_type(8))) short;
using ushort4v = __attribute__((ext_vector_type(4))) unsigned short;
using f32x4    = __attribute__((ext_vector_type(4))) float;
using int4v    = __attribute__((ext_vector_type(4))) int;

__device__ __forceinline__ unsigned short f2bf(float f) {
    unsigned u = __builtin_bit_cast(unsigned, f);
    u += 0x7FFFu + ((u >> 16) & 1u);          // RNE
    return (unsigned short)(u >> 16);
}
__device__ __forceinline__ float bf2f(unsigned short s) {
    unsigned u = ((unsigned)s) << 16;
    return __builtin_bit_cast(float, u);
}
__device__ __forceinline__ float frcp(float x) { return __builtin_amdgcn_rcpf(x); }
// rcp-based: exp overflow -> inf -> rcp -> 0 (correct saturation)
__device__ __forceinline__ float sigm(float x)  { return frcp(1.f + __expf(-x)); }
__device__ __forceinline__ float ftanh(float x) { return 1.f - 2.f * frcp(__expf(2.f * x) + 1.f); }

// Barrier that waits ONLY on LDS ops (lgkmcnt), leaving global loads/stores
// (vmcnt) in flight across it. __syncthreads() would drain vmcnt(0) and
// serialize the X prefetch against the barrier every step.
__device__ __forceinline__ void lds_barrier() {
    asm volatile("s_waitcnt lgkmcnt(0)" ::: "memory");
    __builtin_amdgcn_s_barrier();
    asm volatile("" ::: "memory");
}

#define WH_SCALE 512.f
#define H_SCALE  127.f

// Counting sort of the 1024 rows by length, DESCENDING. perm[rank] = orig row.
__global__ __launch_bounds__(1024)
void sort_kernel(const int* __restrict__ lenq, const int* __restrict__ lenr,
                 int* __restrict__ perm, float* __restrict__ out)
{
    __shared__ int cnt[64];
    const int tid = threadIdx.x;
    if (tid == 0) out[0] = 0.f;
    if (tid < 64) cnt[tid] = 0;
    __syncthreads();
    const int l = (tid < 512) ? lenq[tid] : lenr[tid - 512];   // 1..49
    atomicAdd(&cnt[l], 1);
    __syncthreads();
    if (tid == 0) {
        int acc = 0;
        for (int v = 49; v >= 1; --v) { int c = cnt[v]; cnt[v] = acc; acc += c; }
    }
    __syncthreads();
    const int rank = atomicAdd(&cnt[l], 1);
    perm[rank] = tid;
}

// Pack W (f32 [512][1024]):
//  y=0: Wx rows 0..255   -> Wxp bf16 [c][k] col-major frag layout
//  y=1: Wh rows 256..511 -> Wq  int8 [c][k] col-major, scaled by 512
__global__ __launch_bounds__(256)
void pack_w_kernel(const float* __restrict__ W,
                   unsigned short* __restrict__ Wxp, signed char* __restrict__ Wq)
{
    __shared__ float ld[64][65];
    const int koff = blockIdx.y * 256;
    const int k0 = (blockIdx.x & 3) * 64, c0 = (blockIdx.x >> 2) * 64;
    const int tid = threadIdx.x;
    #pragma unroll
    for (int i = 0; i < 16; ++i) {
        int idx = tid + i * 256;
        ld[idx >> 6][idx & 63] = W[(size_t)(koff + k0 + (idx >> 6)) * 1024 + c0 + (idx & 63)];
    }
    __syncthreads();
    if (blockIdx.y == 0) {
        #pragma unroll
        for (int j = 0; j < 2; ++j) {
            int idx = tid + j * 256;
            int cl = idx >> 3, kc = (idx & 7) * 8;
            short8 v;
            #pragma unroll
            for (int e = 0; e < 8; ++e) v[e] = (short)f2bf(ld[kc + e][cl]);
            *(short8*)(Wxp + (size_t)(c0 + cl) * 256 + k0 + kc) = v;
        }
    } else {
        #pragma unroll
        for (int j = 0; j < 2; ++j) {
            int idx = tid + j * 256;
            int cl = idx >> 3, kc = (idx & 7) * 8;
            unsigned long long u = 0;
            #pragma unroll
            for (int e = 0; e < 8; ++e) {
                float v = ld[kc + e][cl] * WH_SCALE;
                int q = __float2int_rn(fminf(fmaxf(v, -127.f), 127.f));
                u |= (unsigned long long)(unsigned char)(signed char)q << (8 * e);
            }
            *(unsigned long long*)(Wq + (size_t)(c0 + cl) * 256 + k0 + kc) = u;
        }
    }
}

// X projection v5: rows processed in SORTED order (perm). Per-it whole-tile
// skip when t >= max length in the tile (sorted desc -> first row is max).
// Wx register-resident; block = 512 thr owns a 256-col slice (y of 4),
// sweeps 4 row-tiles. Bias (+FORGET_BIAS) folded into the stored X.
// In-loop barriers are lgkmcnt-only (X stores stay in flight).
// X element offset: t*1048576 + rblk*16384 + slot*256 + L*4  (slot = zcol/16)
__global__ __launch_bounds__(512, 4)
void xproj_kernel(const float* __restrict__ emb,
                  const int* __restrict__ idq, const int* __restrict__ idr,
                  const int* __restrict__ lenq, const int* __restrict__ lenr,
                  const int* __restrict__ perm,
                  const unsigned short* __restrict__ Wxp,
                  const float* __restrict__ bias,
                  unsigned short* __restrict__ X)
{
    __shared__ __align__(16) unsigned short As[64 * 264];   // 33 KB
    __shared__ int Ls2[4][64];
    __shared__ int Ids2[4][64];
    __shared__ int Tmax[4];

    const int tid = threadIdx.x;
    const int L = tid & 63, w = tid >> 6;          // 8 waves
    const int lanelo = L & 15, lhi = L >> 4;
    const int cslice = blockIdx.y;                 // 0..3
    const int colbase = cslice * 256 + w * 32;     // wave's 32 cols
    const int slot0 = cslice * 16 + w * 2;

    // ---- Wx slice -> registers (persistent; lands in AGPRs) ----
    short8 Bx[2][8];
    #pragma unroll
    for (int cf = 0; cf < 2; ++cf) {
        const unsigned short* bb = Wxp + (size_t)(colbase + cf * 16 + lanelo) * 256 + lhi * 8;
        #pragma unroll
        for (int ks = 0; ks < 8; ++ks) Bx[cf][ks] = *(const short8*)(bb + ks * 32);
    }
    // per-lane bias for the two owned cols (incl. forget bias on gate 2)
    float bc[2];
    #pragma unroll
    for (int cf = 0; cf < 2; ++cf) {
        int col = colbase + cf * 16 + lanelo;
        bc[cf] = bias[col] + ((col >= 512 && col < 768) ? 2.0f : 0.f);
    }

    // ---- stage lens/ids (sorted order) for this block's 4 row-tiles ----
    if (tid < 256) {
        int it = tid >> 6, rl = tid & 63;
        int rt = blockIdx.x + it * 196;
        int t = rt >> 4, r0 = (rt & 15) * 64;
        int gr = perm[r0 + rl];
        int len = (gr < 512) ? lenq[gr] : lenr[gr - 512];
        Ls2[it][rl] = len;
        Ids2[it][rl] = (gr < 512) ? idq[gr * TTs + t] : idr[(gr - 512) * TTs + t];
        if (rl == 0) Tmax[it] = len;               // sorted desc -> max of tile
    }
    __syncthreads();

    for (int it = 0; it < 4; ++it) {
        const int rt = blockIdx.x + it * 196;
        const int t = rt >> 4;
        const int rblkb = (rt & 15) * 4;
        if (t >= Tmax[it]) continue;               // whole tile dead (uniform)
        const int* Ls = Ls2[it];
        const int* Ids = Ids2[it];

        // ---- stage gathered emb rows -> LDS (bf16), skip dead rows ----
        float4 ev0[4], ev1[4];
        bool live[4];
        #pragma unroll
        for (int i = 0; i < 4; ++i) {
            int task = tid + i * 512;
            int rl = task >> 5, kc = (task & 31) * 8;
            live[i] = (t < Ls[rl]);
            if (live[i]) {
                const float* ep = emb + (size_t)Ids[rl] * 256 + kc;
                ev0[i] = *(const float4*)ep;
                ev1[i] = *(const float4*)(ep + 4);
            }
        }
        #pragma unroll
        for (int i = 0; i < 4; ++i) {
            if (live[i]) {
                int task = tid + i * 512;
                int rl = task >> 5, kc = (task & 31) * 8;
                short8 v;
                v[0] = (short)f2bf(ev0[i].x); v[1] = (short)f2bf(ev0[i].y);
                v[2] = (short)f2bf(ev0[i].z); v[3] = (short)f2bf(ev0[i].w);
                v[4] = (short)f2bf(ev1[i].x); v[5] = (short)f2bf(ev1[i].y);
                v[6] = (short)f2bf(ev1[i].z); v[7] = (short)f2bf(ev1[i].w);
                *(short8*)(As + rl * 264 + kc) = v;
            }
        }
        lds_barrier();

        // ---- compute: 4 row-groups x (8 ds_read + 16 MFMA) ----
        #pragma unroll
        for (int rg = 0; rg < 4; ++rg) {
            int base = rg * 16 + lhi * 4;
            int lmax = max(max(Ls[base], Ls[base + 1]), max(Ls[base + 2], Ls[base + 3]));
            bool myalive = (t < lmax);
            if (__any(myalive)) {
                f32x4 a0 = (f32x4){0.f, 0.f, 0.f, 0.f};
                f32x4 a1 = (f32x4){0.f, 0.f, 0.f, 0.f};
                const unsigned short* ar = As + (rg * 16 + lanelo) * 264 + lhi * 8;
                #pragma unroll
                for (int ks = 0; ks < 8; ++ks) {
                    short8 a = *(const short8*)(ar + ks * 32);
                    a0 = __builtin_amdgcn_mfma_f32_16x16x32_bf16(a, Bx[0][ks], a0, 0, 0, 0);
                    a1 = __builtin_amdgcn_mfma_f32_16x16x32_bf16(a, Bx[1][ks], a1, 0, 0, 0);
                }
                if (myalive) {
                    size_t off = (((size_t)(t * 64 + rblkb + rg)) * 64 + slot0) * 256 + L * 4;
                    ushort4v v0, v1;
                    #pragma unroll
                    for (int j = 0; j < 4; ++j) {
                        v0[j] = f2bf(a0[j] + bc[0]);
                        v1[j] = f2bf(a1[j] + bc[1]);
                    }
                    *(ushort4v*)(X + off) = v0;
                    *(ushort4v*)(X + off + 256) = v1;
                }
            }
        }
        lds_barrier();     // protect As/Ls before next tile's staging
    }
}

// Recurrent loop v7 (r12 shape + counted-vmcnt barrier): 256 blocks x 4
// SORTED rows, 16 waves, all 256 CUs, __launch_bounds__(1024,4) so the
// 64-reg Wh slice stays AGPR-resident (r14's (1024,8) forced a spill).
// In-loop barrier waits lgkmcnt ONLY -> the one-step-ahead X prefetch
// actually stays in flight across the barrier (its vmcnt wait lands at the
// xr=xn copy AFTER the barrier, a full step after issue).
__global__ __launch_bounds__(1024, 4)
void lstm_i8_kernel(const unsigned short* __restrict__ X,
                    const signed char* __restrict__ Wq,
                    const float* __restrict__ p_i, const float* __restrict__ p_f,
                    const float* __restrict__ p_o,
                    const int* __restrict__ lenq, const int* __restrict__ lenr,
                    const int* __restrict__ perm,
                    unsigned short* __restrict__ hfin)
{
    __shared__ __align__(16) char hl[2 * 4 * 288];   // 2304 B, dbuf x 4 rows
    const int tid = threadIdx.x;
    const int L = tid & 63, w = tid >> 6;      // w 0..15
    const int blk = blockIdx.x;                // 4 sorted rows each
    const int lanelo = L & 15, lhi = L >> 4;
    const int hh = w * 16 + lanelo;

    if (tid < 576) ((int*)hl)[tid] = 0;

    // ---- Wh slice (int8) -> registers (AGPR-resident), persistent ----
    int4v Bw[4][4];
    #pragma unroll
    for (int g = 0; g < 4; ++g)
        #pragma unroll
        for (int kc = 0; kc < 4; ++kc)
            Bw[g][kc] = *(const int4v*)(Wq + (size_t)(g * 256 + hh) * 256 + kc * 64 + lhi * 16);

    // X addressing (sorted positions): tile rblk16 = blk>>2, tr = (blk&3)*4+lhi
    // ushort element offset: (g*16+w)*256 + (blk&3)*64 + lanelo*4 + lhi
    const unsigned short* xb = X + (size_t)(blk >> 2) * 16384;
    int xgoff[4];
    #pragma unroll
    for (int g = 0; g < 4; ++g)
        xgoff[g] = (g * 16 + w) * 256 + (blk & 3) * 64 + lanelo * 4 + lhi;

    const bool rdlane = (lanelo & 3) == 0;     // 16 lanes read; rest hold zeros
    const int ard = (lanelo >> 2) * 288 + lhi * 16;  // live row = lanelo>>2
    const int awr = lhi * 288 + hh;                   // live row = lhi

    const float pii = p_i[hh], pff = p_f[hh], poo = p_o[hh];
    const float INV = 1.f / (H_SCALE * WH_SCALE);

    const int gr = perm[blk * 4 + lhi];
    const int len_ = (gr < 512) ? lenq[gr] : lenr[gr - 512];
    const int p0 = perm[blk * 4];
    const int blkmax = (p0 < 512) ? lenq[p0] : lenr[p0 - 512];  // uniform

    float cst = 0.f;
    float hst = 0.f;

    // A-fragments: rows != 4k are permanently zero (init hoisted out of loop)
    int4v a[4];
    #pragma unroll
    for (int kc = 0; kc < 4; ++kc) a[kc] = (int4v){0, 0, 0, 0};

    // preload X for t = 0 (always written: len >= 1)
    unsigned short xr[4], xn[4];
    #pragma unroll
    for (int g = 0; g < 4; ++g) xr[g] = xb[xgoff[g]];
    const unsigned short* xp = xb + 1048576;   // scalar, advances 1 MB/step

    __syncthreads();

    for (int t = 0; t < blkmax; ++t) {
        const int rb = (t & 1) * 1152;
        const int wb = 1152 - rb;

        // prefetch next step (uniform cselect keeps the last read in-bounds);
        // these loads cross the lgkm-only barrier and are waited on only at
        // the xr=xn copy after it -> a full step of latency hiding.
        const unsigned short* xs = (t + 1 < blkmax) ? xp : xb;
        #pragma unroll
        for (int g = 0; g < 4; ++g) xn[g] = xs[xgoff[g]];
        xp += 1048576;

        if (rdlane) {
            #pragma unroll
            for (int kc = 0; kc < 4; ++kc)
                a[kc] = *(const int4v*)(hl + rb + ard + kc * 64);
        }

        int4v acc[4];
        #pragma unroll
        for (int g = 0; g < 4; ++g) acc[g] = (int4v){0, 0, 0, 0};
        #pragma unroll
        for (int kc = 0; kc < 4; ++kc)
            #pragma unroll
            for (int g = 0; g < 4; ++g)
                acc[g] = __builtin_amdgcn_mfma_i32_16x16x64_i8(a[kc], Bw[g][kc], acc[g], 0, 0, 0);

        {
            float cv = cst;
            float zi = fmaf((float)acc[0][0], INV, bf2f(xr[0]));
            float zj = fmaf((float)acc[1][0], INV, bf2f(xr[1]));
            float zf = fmaf((float)acc[2][0], INV, bf2f(xr[2]));
            float zo = fmaf((float)acc[3][0], INV, bf2f(xr[3]));
            float iv = sigm(fmaf(pii, cv, zi));
            float fv = sigm(fmaf(pff, cv, zf));
            float jv = ftanh(zj);
            float cn = fv * cv + iv * jv;
            float ov = sigm(fmaf(poo, cn, zo));
            float hn = ov * ftanh(cn);
            bool upd = (t < len_);
            if (upd) { cst = cn; hst = hn; }
            hl[wb + awr] = (signed char)__float2int_rn(hst * H_SCALE);
        }
        lds_barrier();
        #pragma unroll
        for (int g = 0; g < 4; ++g) xr[g] = xn[g];
    }

    hfin[(size_t)gr * 256 + hh] = f2bf(hst);
}

#define TS 64
#define KT 16
#define LDW (TS + 4)

// qM[512x256] = bf16 h(rows 0..511) @ fp32 M[256x256]
__global__ __launch_bounds__(256)
void gemm_qM_kernel(const unsigned short* __restrict__ hA, const float* __restrict__ B,
                    float* __restrict__ C)
{
    __shared__ float As[KT][LDW];
    __shared__ float Bs[KT][LDW];
    const int tid = threadIdx.x;
    const int tx = tid & 15, ty = tid >> 4;
    const int m0 = blockIdx.x * TS, n0 = blockIdx.y * TS;
    float acc[4][4] = {};
    for (int kk = 0; kk < 256; kk += KT) {
        #pragma unroll
        for (int i = 0; i < 4; ++i) {
            int l = tid + i * 256;
            As[l & 15][l >> 4] = bf2f(hA[(m0 + (l >> 4)) * 256 + kk + (l & 15)]);
            Bs[l >> 6][l & 63] = B[(kk + (l >> 6)) * 256 + n0 + (l & 63)];
        }
        __syncthreads();
        #pragma unroll
        for (int k = 0; k < KT; ++k) {
            float4 a4 = *(const float4*)&As[k][ty * 4];
            float4 b4 = *(const float4*)&Bs[k][tx * 4];
            float av[4] = {a4.x, a4.y, a4.z, a4.w};
            float bv[4] = {b4.x, b4.y, b4.z, b4.w};
            #pragma unroll
            for (int i = 0; i < 4; ++i)
                #pragma unroll
                for (int j = 0; j < 4; ++j)
                    acc[i][j] = fmaf(av[i], bv[j], acc[i][j]);
        }
        __syncthreads();
    }
    #pragma unroll
    for (int i = 0; i < 4; ++i) {
        float4 v = {acc[i][0], acc[i][1], acc[i][2], acc[i][3]};
        *(float4*)&C[(m0 + ty * 4 + i) * 256 + n0 + tx * 4] = v;
    }
}

// D[512x512] = fp32 qM[512x256] @ (bf16 r[512x256])^T
__global__ __launch_bounds__(256)
void gemm_D_kernel(const float* __restrict__ A, const unsigned short* __restrict__ hB,
                   float* __restrict__ C)
{
    __shared__ float As[KT][LDW];
    __shared__ float Bs[KT][LDW];
    const int tid = threadIdx.x;
    const int tx = tid & 15, ty = tid >> 4;
    const int m0 = blockIdx.x * TS, n0 = blockIdx.y * TS;
    float acc[4][4] = {};
    for (int kk = 0; kk < 256; kk += KT) {
        #pragma unroll
        for (int i = 0; i < 4; ++i) {
            int l = tid + i * 256;
            As[l & 15][l >> 4] = A[(m0 + (l >> 4)) * 256 + kk + (l & 15)];
            Bs[l & 15][l >> 4] = bf2f(hB[(n0 + (l >> 4)) * 256 + kk + (l & 15)]);
        }
        __syncthreads();
        #pragma unroll
        for (int k = 0; k < KT; ++k) {
            float4 a4 = *(const float4*)&As[k][ty * 4];
            float4 b4 = *(const float4*)&Bs[k][tx * 4];
            float av[4] = {a4.x, a4.y, a4.z, a4.w};
            float bv[4] = {b4.x, b4.y, b4.z, b4.w};
            #pragma unroll
            for (int i = 0; i < 4; ++i)
                #pragma unroll
                for (int j = 0; j < 4; ++j)
                    acc[i][j] = fmaf(av[i], bv[j], acc[i][j]);
        }
        __syncthreads();
    }
    #pragma unroll
    for (int i = 0; i < 4; ++i) {
        float4 v = {acc[i][0], acc[i][1], acc[i][2], acc[i][3]};
        *(float4*)&C[(m0 + ty * 4 + i) * 512 + n0 + tx * 4] = v;
    }
}

__global__ __launch_bounds__(256)
void loss_kernel(const float* __restrict__ D, const float* __restrict__ wd,
                 float* __restrict__ out)
{
    int idx = blockIdx.x * 256 + threadIdx.x;
    int j = idx & 511;
    float d   = D[idx];
    float pos = D[j * 512 + j];
    float ww  = wd[idx];
    float wp  = wd[j * 512 + j];
    float wn  = fmaxf(0.f, fmaf(ww, frcp(wp), -1.f));
    float v   = fmaxf(0.f, d - pos + wn);
    #pragma unroll
    for (int o = 32; o > 0; o >>= 1) v += __shfl_down(v, o);
    __shared__ float sm[4];
    if ((threadIdx.x & 63) == 0) sm[threadIdx.x >> 6] = v;
    __syncthreads();
    if (threadIdx.x == 0) atomicAdd(out, sm[0] + sm[1] + sm[2] + sm[3]);
}

extern "C" void kernel_launch(void* const* d_in, const int* in_sizes, int n_in,
                              void* d_out, int out_size, void* d_ws, size_t ws_size,
                              hipStream_t stream) {
    const int*   idq  = (const int*)d_in[0];
    const int*   idr  = (const int*)d_in[1];
    const int*   lenq = (const int*)d_in[2];
    const int*   lenr = (const int*)d_in[3];
    const float* wd   = (const float*)d_in[4];
    const float* emb  = (const float*)d_in[5];
    const float* W    = (const float*)d_in[6];
    const float* bias = (const float*)d_in[7];
    const float* p_i  = (const float*)d_in[8];
    const float* p_f  = (const float*)d_in[9];
    const float* p_o  = (const float*)d_in[10];
    const float* Mm   = (const float*)d_in[11];
    float* out = (float*)d_out;

    char* ws = (char*)d_ws;
    unsigned short* X    = (unsigned short*)ws;           // 49*1024*1024 bf16 = 102,760,448 B
    char* p = ws + (size_t)NSTEP * 1048576 * 2;
    unsigned short* hfin = (unsigned short*)p;  p += 1024 * 256 * 2;   // 512 KB
    unsigned short* Wxp  = (unsigned short*)p;  p += 1024 * 256 * 2;   // 512 KB
    signed char*    Wq   = (signed char*)p;     p += 1024 * 256;       // 256 KB
    float* qM = (float*)p;  p += 512 * 256 * 4;                        // 512 KB
    float* D  = (float*)p;  p += 512 * 512 * 4;                        // 1 MB
    int* perm = (int*)p;                                               // 4 KB

    sort_kernel<<<1, 1024, 0, stream>>>(lenq, lenr, perm, out);
    pack_w_kernel<<<dim3(64, 2), 256, 0, stream>>>(W, Wxp, Wq);
    xproj_kernel<<<dim3(196, 4), 512, 0, stream>>>(emb, idq, idr, lenq, lenr,
                                                   perm, Wxp, bias, X);
    lstm_i8_kernel<<<256, 1024, 0, stream>>>(X, Wq, p_i, p_f, p_o,
                                             lenq, lenr, perm, hfin);
    gemm_qM_kernel<<<dim3(8, 4), 256, 0, stream>>>(hfin, Mm, qM);
    gemm_D_kernel<<<dim3(8, 8), 256, 0, stream>>>(qM, hfin + 512 * 256, D);
    loss_kernel<<<1024, 256, 0, stream>>>(D, wd, out);
}

// Round 16
// 136.506 us; speedup vs baseline: 4.7951x; 1.0999x over previous
//
#include <hip/hip_runtime.h>

#define TTs 50
#define NSTEP 49

using short8   = __attribute__((ext_vector_type(8))) short;
using ushort4v = __attribute__((ext_vector_type(4))) unsigned short;
using f32x4    = __attribute__((ext_vector_type(4))) float;
using int4v    = __attribute__((ext_vector_type(4))) int;

__device__ __forceinline__ unsigned short f2bf(float f) {
    unsigned u = __builtin_bit_cast(unsigned, f);
    u += 0x7FFFu + ((u >> 16) & 1u);          // RNE
    return (unsigned short)(u >> 16);
}
__device__ __forceinline__ float bf2f(unsigned short s) {
    unsigned u = ((unsigned)s) << 16;
    return __builtin_bit_cast(float, u);
}
__device__ __forceinline__ float frcp(float x) { return __builtin_amdgcn_rcpf(x); }
// rcp-based: exp overflow -> inf -> rcp -> 0 (correct saturation)
__device__ __forceinline__ float sigm(float x)  { return frcp(1.f + __expf(-x)); }
__device__ __forceinline__ float ftanh(float x) { return 1.f - 2.f * frcp(__expf(2.f * x) + 1.f); }

// Barrier that waits ONLY on LDS ops (lgkmcnt), leaving global loads/stores
// (vmcnt) in flight across it.
__device__ __forceinline__ void lds_barrier() {
    asm volatile("s_waitcnt lgkmcnt(0)" ::: "memory");
    __builtin_amdgcn_s_barrier();
    asm volatile("" ::: "memory");
}

#define WH_SCALE 512.f
#define H_SCALE  127.f

// Counting sort of the 1024 rows by length, DESCENDING. perm[rank] = orig row.
__global__ __launch_bounds__(1024)
void sort_kernel(const int* __restrict__ lenq, const int* __restrict__ lenr,
                 int* __restrict__ perm, float* __restrict__ out)
{
    __shared__ int cnt[64];
    const int tid = threadIdx.x;
    if (tid == 0) out[0] = 0.f;
    if (tid < 64) cnt[tid] = 0;
    __syncthreads();
    const int l = (tid < 512) ? lenq[tid] : lenr[tid - 512];   // 1..49
    atomicAdd(&cnt[l], 1);
    __syncthreads();
    if (tid == 0) {
        int acc = 0;
        for (int v = 49; v >= 1; --v) { int c = cnt[v]; cnt[v] = acc; acc += c; }
    }
    __syncthreads();
    const int rank = atomicAdd(&cnt[l], 1);
    perm[rank] = tid;
}

// Pack W (f32 [512][1024]):
//  y=0: Wx rows 0..255   -> Wxp bf16 [c][k] col-major frag layout
//  y=1: Wh rows 256..511 -> Wq  int8 [c][k] col-major, scaled by 512
__global__ __launch_bounds__(256)
void pack_w_kernel(const float* __restrict__ W,
                   unsigned short* __restrict__ Wxp, signed char* __restrict__ Wq)
{
    __shared__ float ld[64][65];
    const int koff = blockIdx.y * 256;
    const int k0 = (blockIdx.x & 3) * 64, c0 = (blockIdx.x >> 2) * 64;
    const int tid = threadIdx.x;
    #pragma unroll
    for (int i = 0; i < 16; ++i) {
        int idx = tid + i * 256;
        ld[idx >> 6][idx & 63] = W[(size_t)(koff + k0 + (idx >> 6)) * 1024 + c0 + (idx & 63)];
    }
    __syncthreads();
    if (blockIdx.y == 0) {
        #pragma unroll
        for (int j = 0; j < 2; ++j) {
            int idx = tid + j * 256;
            int cl = idx >> 3, kc = (idx & 7) * 8;
            short8 v;
            #pragma unroll
            for (int e = 0; e < 8; ++e) v[e] = (short)f2bf(ld[kc + e][cl]);
            *(short8*)(Wxp + (size_t)(c0 + cl) * 256 + k0 + kc) = v;
        }
    } else {
        #pragma unroll
        for (int j = 0; j < 2; ++j) {
            int idx = tid + j * 256;
            int cl = idx >> 3, kc = (idx & 7) * 8;
            unsigned long long u = 0;
            #pragma unroll
            for (int e = 0; e < 8; ++e) {
                float v = ld[kc + e][cl] * WH_SCALE;
                int q = __float2int_rn(fminf(fmaxf(v, -127.f), 127.f));
                u |= (unsigned long long)(unsigned char)(signed char)q << (8 * e);
            }
            *(unsigned long long*)(Wq + (size_t)(c0 + cl) * 256 + k0 + kc) = u;
        }
    }
}

// X projection v5 (unchanged from r15).
__global__ __launch_bounds__(512, 4)
void xproj_kernel(const float* __restrict__ emb,
                  const int* __restrict__ idq, const int* __restrict__ idr,
                  const int* __restrict__ lenq, const int* __restrict__ lenr,
                  const int* __restrict__ perm,
                  const unsigned short* __restrict__ Wxp,
                  const float* __restrict__ bias,
                  unsigned short* __restrict__ X)
{
    __shared__ __align__(16) unsigned short As[64 * 264];   // 33 KB
    __shared__ int Ls2[4][64];
    __shared__ int Ids2[4][64];
    __shared__ int Tmax[4];

    const int tid = threadIdx.x;
    const int L = tid & 63, w = tid >> 6;          // 8 waves
    const int lanelo = L & 15, lhi = L >> 4;
    const int cslice = blockIdx.y;                 // 0..3
    const int colbase = cslice * 256 + w * 32;     // wave's 32 cols
    const int slot0 = cslice * 16 + w * 2;

    // ---- Wx slice -> registers (persistent; lands in AGPRs) ----
    short8 Bx[2][8];
    #pragma unroll
    for (int cf = 0; cf < 2; ++cf) {
        const unsigned short* bb = Wxp + (size_t)(colbase + cf * 16 + lanelo) * 256 + lhi * 8;
        #pragma unroll
        for (int ks = 0; ks < 8; ++ks) Bx[cf][ks] = *(const short8*)(bb + ks * 32);
    }
    float bc[2];
    #pragma unroll
    for (int cf = 0; cf < 2; ++cf) {
        int col = colbase + cf * 16 + lanelo;
        bc[cf] = bias[col] + ((col >= 512 && col < 768) ? 2.0f : 0.f);
    }

    if (tid < 256) {
        int it = tid >> 6, rl = tid & 63;
        int rt = blockIdx.x + it * 196;
        int t = rt >> 4, r0 = (rt & 15) * 64;
        int gr = perm[r0 + rl];
        int len = (gr < 512) ? lenq[gr] : lenr[gr - 512];
        Ls2[it][rl] = len;
        Ids2[it][rl] = (gr < 512) ? idq[gr * TTs + t] : idr[(gr - 512) * TTs + t];
        if (rl == 0) Tmax[it] = len;               // sorted desc -> max of tile
    }
    __syncthreads();

    for (int it = 0; it < 4; ++it) {
        const int rt = blockIdx.x + it * 196;
        const int t = rt >> 4;
        const int rblkb = (rt & 15) * 4;
        if (t >= Tmax[it]) continue;               // whole tile dead (uniform)
        const int* Ls = Ls2[it];
        const int* Ids = Ids2[it];

        float4 ev0[4], ev1[4];
        bool live[4];
        #pragma unroll
        for (int i = 0; i < 4; ++i) {
            int task = tid + i * 512;
            int rl = task >> 5, kc = (task & 31) * 8;
            live[i] = (t < Ls[rl]);
            if (live[i]) {
                const float* ep = emb + (size_t)Ids[rl] * 256 + kc;
                ev0[i] = *(const float4*)ep;
                ev1[i] = *(const float4*)(ep + 4);
            }
        }
        #pragma unroll
        for (int i = 0; i < 4; ++i) {
            if (live[i]) {
                int task = tid + i * 512;
                int rl = task >> 5, kc = (task & 31) * 8;
                short8 v;
                v[0] = (short)f2bf(ev0[i].x); v[1] = (short)f2bf(ev0[i].y);
                v[2] = (short)f2bf(ev0[i].z); v[3] = (short)f2bf(ev0[i].w);
                v[4] = (short)f2bf(ev1[i].x); v[5] = (short)f2bf(ev1[i].y);
                v[6] = (short)f2bf(ev1[i].z); v[7] = (short)f2bf(ev1[i].w);
                *(short8*)(As + rl * 264 + kc) = v;
            }
        }
        lds_barrier();

        #pragma unroll
        for (int rg = 0; rg < 4; ++rg) {
            int base = rg * 16 + lhi * 4;
            int lmax = max(max(Ls[base], Ls[base + 1]), max(Ls[base + 2], Ls[base + 3]));
            bool myalive = (t < lmax);
            if (__any(myalive)) {
                f32x4 a0 = (f32x4){0.f, 0.f, 0.f, 0.f};
                f32x4 a1 = (f32x4){0.f, 0.f, 0.f, 0.f};
                const unsigned short* ar = As + (rg * 16 + lanelo) * 264 + lhi * 8;
                #pragma unroll
                for (int ks = 0; ks < 8; ++ks) {
                    short8 a = *(const short8*)(ar + ks * 32);
                    a0 = __builtin_amdgcn_mfma_f32_16x16x32_bf16(a, Bx[0][ks], a0, 0, 0, 0);
                    a1 = __builtin_amdgcn_mfma_f32_16x16x32_bf16(a, Bx[1][ks], a1, 0, 0, 0);
                }
                if (myalive) {
                    size_t off = (((size_t)(t * 64 + rblkb + rg)) * 64 + slot0) * 256 + L * 4;
                    ushort4v v0, v1;
                    #pragma unroll
                    for (int j = 0; j < 4; ++j) {
                        v0[j] = f2bf(a0[j] + bc[0]);
                        v1[j] = f2bf(a1[j] + bc[1]);
                    }
                    *(ushort4v*)(X + off) = v0;
                    *(ushort4v*)(X + off + 256) = v1;
                }
            }
        }
        lds_barrier();
    }
}

// Recurrent loop v7 (unchanged from r15): 256 blocks x 4 SORTED rows,
// 16 waves, Whq AGPR-resident, lgkm-only in-loop barrier.
__global__ __launch_bounds__(1024, 4)
void lstm_i8_kernel(const unsigned short* __restrict__ X,
                    const signed char* __restrict__ Wq,
                    const float* __restrict__ p_i, const float* __restrict__ p_f,
                    const float* __restrict__ p_o,
                    const int* __restrict__ lenq, const int* __restrict__ lenr,
                    const int* __restrict__ perm,
                    unsigned short* __restrict__ hfin)
{
    __shared__ __align__(16) char hl[2 * 4 * 288];   // 2304 B, dbuf x 4 rows
    const int tid = threadIdx.x;
    const int L = tid & 63, w = tid >> 6;      // w 0..15
    const int blk = blockIdx.x;                // 4 sorted rows each
    const int lanelo = L & 15, lhi = L >> 4;
    const int hh = w * 16 + lanelo;

    if (tid < 576) ((int*)hl)[tid] = 0;

    int4v Bw[4][4];
    #pragma unroll
    for (int g = 0; g < 4; ++g)
        #pragma unroll
        for (int kc = 0; kc < 4; ++kc)
            Bw[g][kc] = *(const int4v*)(Wq + (size_t)(g * 256 + hh) * 256 + kc * 64 + lhi * 16);

    const unsigned short* xb = X + (size_t)(blk >> 2) * 16384;
    int xgoff[4];
    #pragma unroll
    for (int g = 0; g < 4; ++g)
        xgoff[g] = (g * 16 + w) * 256 + (blk & 3) * 64 + lanelo * 4 + lhi;

    const bool rdlane = (lanelo & 3) == 0;
    const int ard = (lanelo >> 2) * 288 + lhi * 16;
    const int awr = lhi * 288 + hh;

    const float pii = p_i[hh], pff = p_f[hh], poo = p_o[hh];
    const float INV = 1.f / (H_SCALE * WH_SCALE);

    const int gr = perm[blk * 4 + lhi];
    const int len_ = (gr < 512) ? lenq[gr] : lenr[gr - 512];
    const int p0 = perm[blk * 4];
    const int blkmax = (p0 < 512) ? lenq[p0] : lenr[p0 - 512];

    float cst = 0.f;
    float hst = 0.f;

    int4v a[4];
    #pragma unroll
    for (int kc = 0; kc < 4; ++kc) a[kc] = (int4v){0, 0, 0, 0};

    unsigned short xr[4], xn[4];
    #pragma unroll
    for (int g = 0; g < 4; ++g) xr[g] = xb[xgoff[g]];
    const unsigned short* xp = xb + 1048576;

    __syncthreads();

    for (int t = 0; t < blkmax; ++t) {
        const int rb = (t & 1) * 1152;
        const int wb = 1152 - rb;

        const unsigned short* xs = (t + 1 < blkmax) ? xp : xb;
        #pragma unroll
        for (int g = 0; g < 4; ++g) xn[g] = xs[xgoff[g]];
        xp += 1048576;

        if (rdlane) {
            #pragma unroll
            for (int kc = 0; kc < 4; ++kc)
                a[kc] = *(const int4v*)(hl + rb + ard + kc * 64);
        }

        int4v acc[4];
        #pragma unroll
        for (int g = 0; g < 4; ++g) acc[g] = (int4v){0, 0, 0, 0};
        #pragma unroll
        for (int kc = 0; kc < 4; ++kc)
            #pragma unroll
            for (int g = 0; g < 4; ++g)
                acc[g] = __builtin_amdgcn_mfma_i32_16x16x64_i8(a[kc], Bw[g][kc], acc[g], 0, 0, 0);

        {
            float cv = cst;
            float zi = fmaf((float)acc[0][0], INV, bf2f(xr[0]));
            float zj = fmaf((float)acc[1][0], INV, bf2f(xr[1]));
            float zf = fmaf((float)acc[2][0], INV, bf2f(xr[2]));
            float zo = fmaf((float)acc[3][0], INV, bf2f(xr[3]));
            float iv = sigm(fmaf(pii, cv, zi));
            float fv = sigm(fmaf(pff, cv, zf));
            float jv = ftanh(zj);
            float cn = fv * cv + iv * jv;
            float ov = sigm(fmaf(poo, cn, zo));
            float hn = ov * ftanh(cn);
            bool upd = (t < len_);
            if (upd) { cst = cn; hst = hn; }
            hl[wb + awr] = (signed char)__float2int_rn(hst * H_SCALE);
        }
        lds_barrier();
        #pragma unroll
        for (int g = 0; g < 4; ++g) xr[g] = xn[g];
    }

    hfin[(size_t)gr * 256 + hh] = f2bf(hst);
}

#define TS 64
#define KT 16
#define LDW (TS + 4)

// epi1: qM[512x256] = bf16 q @ fp32 M; ALSO emits deterministic partial
// pos4[bn][row] = sum over this block's 64 cols of qM[row,col]*r[row,col]
// (pos[j] = qM[j]*r[j] summed later in fixed slice order -> no atomics).
__global__ __launch_bounds__(256)
void epi1_kernel(const unsigned short* __restrict__ hA,   // q rows 0..511
                 const unsigned short* __restrict__ hB,   // r rows 0..511
                 const float* __restrict__ B,             // M
                 float* __restrict__ C,                   // qM
                 float* __restrict__ pos4)                // [4][512]
{
    __shared__ float As[KT][LDW];
    __shared__ float Bs[KT][LDW];
    const int tid = threadIdx.x;
    const int tx = tid & 15, ty = tid >> 4;
    const int m0 = blockIdx.x * TS, n0 = blockIdx.y * TS;
    float acc[4][4] = {};
    for (int kk = 0; kk < 256; kk += KT) {
        #pragma unroll
        for (int i = 0; i < 4; ++i) {
            int l = tid + i * 256;
            As[l & 15][l >> 4] = bf2f(hA[(m0 + (l >> 4)) * 256 + kk + (l & 15)]);
            Bs[l >> 6][l & 63] = B[(kk + (l >> 6)) * 256 + n0 + (l & 63)];
        }
        __syncthreads();
        #pragma unroll
        for (int k = 0; k < KT; ++k) {
            float4 a4 = *(const float4*)&As[k][ty * 4];
            float4 b4 = *(const float4*)&Bs[k][tx * 4];
            float av[4] = {a4.x, a4.y, a4.z, a4.w};
            float bv[4] = {b4.x, b4.y, b4.z, b4.w};
            #pragma unroll
            for (int i = 0; i < 4; ++i)
                #pragma unroll
                for (int j = 0; j < 4; ++j)
                    acc[i][j] = fmaf(av[i], bv[j], acc[i][j]);
        }
        __syncthreads();
    }
    #pragma unroll
    for (int i = 0; i < 4; ++i) {
        float4 v = {acc[i][0], acc[i][1], acc[i][2], acc[i][3]};
        *(float4*)&C[(m0 + ty * 4 + i) * 256 + n0 + tx * 4] = v;
    }
    // partial pos over this block's 64 cols (reduce across the 16 tx lanes)
    #pragma unroll
    for (int i = 0; i < 4; ++i) {
        int row = m0 + ty * 4 + i;
        ushort4v rv = *(const ushort4v*)(hB + row * 256 + n0 + tx * 4);
        float p = acc[i][0] * bf2f(rv[0]) + acc[i][1] * bf2f(rv[1])
                + acc[i][2] * bf2f(rv[2]) + acc[i][3] * bf2f(rv[3]);
        p += __shfl_xor(p, 1);
        p += __shfl_xor(p, 2);
        p += __shfl_xor(p, 4);
        p += __shfl_xor(p, 8);
        if (tx == 0) pos4[blockIdx.y * 512 + row] = p;
    }
}

// epi2: D-tile in registers + fused hinge loss (D never materialized).
// loss += max(0, D[i,j] - pos[j] + max(0, wd[i,j]/wd[j,j] - 1))
__global__ __launch_bounds__(256)
void epi2_kernel(const float* __restrict__ A,             // qM
                 const unsigned short* __restrict__ hB,   // r rows 0..511
                 const float* __restrict__ pos4,          // [4][512]
                 const float* __restrict__ wd,
                 float* __restrict__ out)
{
    __shared__ float As[KT][LDW];
    __shared__ float Bs[KT][LDW];
    const int tid = threadIdx.x;
    const int tx = tid & 15, ty = tid >> 4;
    const int m0 = blockIdx.x * TS, n0 = blockIdx.y * TS;
    float acc[4][4] = {};
    for (int kk = 0; kk < 256; kk += KT) {
        #pragma unroll
        for (int i = 0; i < 4; ++i) {
            int l = tid + i * 256;
            As[l & 15][l >> 4] = A[(m0 + (l >> 4)) * 256 + kk + (l & 15)];
            Bs[l & 15][l >> 4] = bf2f(hB[(n0 + (l >> 4)) * 256 + kk + (l & 15)]);
        }
        __syncthreads();
        #pragma unroll
        for (int k = 0; k < KT; ++k) {
            float4 a4 = *(const float4*)&As[k][ty * 4];
            float4 b4 = *(const float4*)&Bs[k][tx * 4];
            float av[4] = {a4.x, a4.y, a4.z, a4.w};
            float bv[4] = {b4.x, b4.y, b4.z, b4.w};
            #pragma unroll
            for (int i = 0; i < 4; ++i)
                #pragma unroll
                for (int j = 0; j < 4; ++j)
                    acc[i][j] = fmaf(av[i], bv[j], acc[i][j]);
        }
        __syncthreads();
    }
    // fused loss over this 64x64 tile
    float pos_j[4], wdj[4];
    #pragma unroll
    for (int j = 0; j < 4; ++j) {
        int jg = n0 + tx * 4 + j;
        pos_j[j] = pos4[jg] + pos4[512 + jg] + pos4[1024 + jg] + pos4[1536 + jg];
        wdj[j] = frcp(wd[jg * 513]);
    }
    float v = 0.f;
    #pragma unroll
    for (int i = 0; i < 4; ++i) {
        int ig = m0 + ty * 4 + i;
        float4 wrow = *(const float4*)(wd + ig * 512 + n0 + tx * 4);
        float wr[4] = {wrow.x, wrow.y, wrow.z, wrow.w};
        #pragma unroll
        for (int j = 0; j < 4; ++j) {
            float wn = fmaxf(0.f, fmaf(wr[j], wdj[j], -1.f));
            v += fmaxf(0.f, acc[i][j] - pos_j[j] + wn);
        }
    }
    #pragma unroll
    for (int o = 32; o > 0; o >>= 1) v += __shfl_down(v, o);
    __shared__ float sm[4];
    if ((threadIdx.x & 63) == 0) sm[threadIdx.x >> 6] = v;
    __syncthreads();
    if (threadIdx.x == 0) atomicAdd(out, sm[0] + sm[1] + sm[2] + sm[3]);
}

extern "C" void kernel_launch(void* const* d_in, const int* in_sizes, int n_in,
                              void* d_out, int out_size, void* d_ws, size_t ws_size,
                              hipStream_t stream) {
    const int*   idq  = (const int*)d_in[0];
    const int*   idr  = (const int*)d_in[1];
    const int*   lenq = (const int*)d_in[2];
    const int*   lenr = (const int*)d_in[3];
    const float* wd   = (const float*)d_in[4];
    const float* emb  = (const float*)d_in[5];
    const float* W    = (const float*)d_in[6];
    const float* bias = (const float*)d_in[7];
    const float* p_i  = (const float*)d_in[8];
    const float* p_f  = (const float*)d_in[9];
    const float* p_o  = (const float*)d_in[10];
    const float* Mm   = (const float*)d_in[11];
    float* out = (float*)d_out;

    char* ws = (char*)d_ws;
    unsigned short* X    = (unsigned short*)ws;           // 49*1024*1024 bf16 = 102,760,448 B
    char* p = ws + (size_t)NSTEP * 1048576 * 2;
    unsigned short* hfin = (unsigned short*)p;  p += 1024 * 256 * 2;   // 512 KB
    unsigned short* Wxp  = (unsigned short*)p;  p += 1024 * 256 * 2;   // 512 KB
    signed char*    Wq   = (signed char*)p;     p += 1024 * 256;       // 256 KB
    float* qM   = (float*)p;  p += 512 * 256 * 4;                      // 512 KB
    float* pos4 = (float*)p;  p += 4 * 512 * 4;                        // 8 KB
    int* perm = (int*)p;                                               // 4 KB

    sort_kernel<<<1, 1024, 0, stream>>>(lenq, lenr, perm, out);
    pack_w_kernel<<<dim3(64, 2), 256, 0, stream>>>(W, Wxp, Wq);
    xproj_kernel<<<dim3(196, 4), 512, 0, stream>>>(emb, idq, idr, lenq, lenr,
                                                   perm, Wxp, bias, X);
    lstm_i8_kernel<<<256, 1024, 0, stream>>>(X, Wq, p_i, p_f, p_o,
                                             lenq, lenr, perm, hfin);
    unsigned short* rfin = hfin + 512 * 256;
    epi1_kernel<<<dim3(8, 4), 256, 0, stream>>>(hfin, rfin, Mm, qM, pos4);
    epi2_kernel<<<dim3(8, 8), 256, 0, stream>>>(qM, rfin, pos4, wd, out);
}